// Round 24
// baseline (209.144 us; speedup 1.0000x reference)
//
#include <hip/hip_runtime.h>

// ---- problem constants ----
#define BB 4
#define SS 2048
#define DD 1024
#define HH 16
#define MM (BB*SS)          // 8192
#define SLOG2E 0.1803368801111204f   // 0.125 * log2(e): folded into Q projection

typedef __attribute__((ext_vector_type(4))) float f32x4;
typedef __attribute__((ext_vector_type(16))) float f32x16;
typedef __attribute__((ext_vector_type(8))) short short8;
typedef __attribute__((ext_vector_type(4))) unsigned int u32x4;
typedef unsigned short u16;

__device__ __forceinline__ u16 f2bf(float f) {
  unsigned int u = __float_as_uint(f);
  u += 0x7FFF + ((u >> 16) & 1);   // RNE
  return (u16)(u >> 16);
}

__device__ __forceinline__ void gload_lds16(const void* g, void* l) {
  __builtin_amdgcn_global_load_lds(
      (__attribute__((address_space(1))) void*)(g),
      (__attribute__((address_space(3))) void*)(l),
      16, 0, 0);
}

__device__ __forceinline__ unsigned pk_bf16(float lo, float hi) {
  unsigned r;
  asm("v_cvt_pk_bf16_f32 %0, %1, %2" : "=v"(r) : "v"(lo), "v"(hi));
  return r;
}

__device__ __forceinline__ float ex2(float x) {
#if __has_builtin(__builtin_amdgcn_exp2f)
  return __builtin_amdgcn_exp2f(x);
#else
  return exp2f(x);
#endif
}

// swap_half(a,b) -> x = {a.lo32, b.lo32}, y = {a.hi32, b.hi32}
__device__ __forceinline__ void swap_half(unsigned a, unsigned b, unsigned& x, unsigned& y) {
#if __has_builtin(__builtin_amdgcn_permlane32_swap)
  auto r = __builtin_amdgcn_permlane32_swap(a, b, false, false);
  x = r[0]; y = r[1];
#else
  unsigned ax = (unsigned)__shfl_xor((int)a, 32, 64);
  unsigned bx = (unsigned)__shfl_xor((int)b, 32, 64);
  bool hb = (threadIdx.x & 32) != 0;
  x = hb ? bx : a;
  y = hb ? b : ax;
#endif
}

__device__ __forceinline__ float xchg_half(float v) {
  unsigned x, y;
  swap_half(__float_as_uint(v), __float_as_uint(v), x, y);
  return __uint_as_float((threadIdx.x & 32) ? x : y);
}

// ---- all 4 weight transposes in one launch: W [K][N] fp32 -> WT [N][K] bf16 ----
__global__ __launch_bounds__(256) void wtrans4_kernel(const float* __restrict__ Wq,
                                                      const float* __restrict__ Wk,
                                                      const float* __restrict__ Wv,
                                                      const float* __restrict__ Wo,
                                                      u16* __restrict__ WT) {
  const int z = blockIdx.z;
  const float* W = (z == 0) ? Wq : (z == 1) ? Wk : (z == 2) ? Wv : Wo;
  u16* dst = WT + (size_t)z * DD * DD;
  __shared__ float t[32][33];
  int n0 = blockIdx.x * 32, k0 = blockIdx.y * 32;
  int tx = threadIdx.x, ty = threadIdx.y;  // 32 x 8
  #pragma unroll
  for (int r = 0; r < 32; r += 8) t[r + ty][tx] = W[(size_t)(k0 + r + ty) * DD + n0 + tx];
  __syncthreads();
  #pragma unroll
  for (int r = 0; r < 32; r += 8) dst[(size_t)(n0 + r + ty) * DD + k0 + tx] = f2bf(t[tx][r + ty]);
}

// ---- V [M][D] bf16 -> per-head V^T : Vtg[(bh*64 + d)*SS + s] ----
__global__ __launch_bounds__(256) void vtrans_kernel(const u16* __restrict__ Vb,
                                                     u16* __restrict__ Vtg) {
  __shared__ u16 T[64][72];
  int bh = blockIdx.x, st = blockIdx.y;
  int b = bh >> 4, h = bh & 15;
  const u16* src = Vb + ((size_t)(b * SS + st * 64)) * DD + h * 64;
  int r = threadIdx.x >> 3;        // 0..31
  int s8 = threadIdx.x & 7;
  #pragma unroll
  for (int half = 0; half < 2; ++half) {
    int row = half * 32 + r;
    short8 vv = *(const short8*)(src + (size_t)row * DD + s8 * 8);
    #pragma unroll
    for (int j = 0; j < 8; ++j) T[row][s8 * 8 + j] = (u16)vv[j];
  }
  __syncthreads();
  u16* dst = Vtg + ((size_t)bh * 64) * SS + st * 64;
  #pragma unroll
  for (int half = 0; half < 2; ++half) {
    int d = half * 32 + r;
    short8 ov;
    #pragma unroll
    for (int j = 0; j < 8; ++j) ov[j] = (short)T[s8 * 8 + j][d];
    *(short8*)(dst + (size_t)d * SS + s8 * 8) = ov;
  }
}

// ---- GEMM: C[M][N] = A[M][K] * Bt[N][K]^T + bias, fp32 acc ----
// AMODE 0: A bf16 in global, gload_lds staging, BK=32 (m97 path).
// AMODE 2: A fp32, reg-staged issue-early (R18-validated), BK=64: halves the
//   barrier-drain count (32->16) and naked-B latency windows. LDS 32KB (no
//   occupancy cliff, cf m132's BK=128 failure at 64KB). LDS frag-read bank
//   aliasing worsens at 128B row stride, but 2-phase schedules hide LDS-read
//   conflicts (m252) — the critical path here is stage+barrier, which BK=64
//   shrinks. B stays single-buffered (R19/R21 dbuf variants measured worse).
// QKV3: fused QKV projection — blockIdx.y in [0,24): sel = y>>3 picks the input
// tensor {q,k,v}, weight panel, bias, output buffer; sel 0 scaled by oscale.
template <int AMODE, int BF16OUT, int QKV3>
__global__ __launch_bounds__(256) void gemm_bt(const void* __restrict__ Ap0, const void* __restrict__ Ap1,
                                               const void* __restrict__ Ap2, const u16* __restrict__ Bt,
                                               const float* __restrict__ b0, const float* __restrict__ b1,
                                               const float* __restrict__ b2, void* __restrict__ Cout,
                                               float oscale, int M, int N, int K) {
  __shared__ __align__(16) u16 As[AMODE == 2 ? 128 * 64 : 128 * 32];
  __shared__ __align__(16) u16 Bs[AMODE == 2 ? 128 * 64 : 128 * 32];
  const int tid = threadIdx.x, lane = tid & 63, wid = tid >> 6;
  const int wr = wid >> 1, wc = wid & 1;
  const int fr = lane & 15, fq = lane >> 4;
  const int mt = blockIdx.x;
  const int ntg = blockIdx.y;
  const int sel = QKV3 ? (ntg >> 3) : 0;
  const int nt = QKV3 ? (ntg & 7) : ntg;
  const void* Ap = QKV3 ? (sel == 0 ? Ap0 : sel == 1 ? Ap1 : Ap2) : Ap0;

  f32x4 acc[4][4];
  #pragma unroll
  for (int m = 0; m < 4; ++m)
    #pragma unroll
    for (int n = 0; n < 4; ++n) acc[m][n] = (f32x4)0.0f;

  const int sRow = lane >> 2;              // bf16 staging (BK=32): 16 rows/KB chunk
  const int sCol = (lane & 3) * 8;

  const float* gA32 = (const float*)Ap + (size_t)(mt * 128) * K;
  const u16*   gA16 = (const u16*)Ap + (size_t)(mt * 128) * K;
  const u16*   gB   = Bt + (QKV3 ? (size_t)sel * DD * DD : 0) + (size_t)(nt * 128) * K;

  if (AMODE == 2) {
    // -------- BK=64 path --------
    const int rA = tid >> 3;               // 0..31 (row within each 32-row group)
    const int cA = (tid & 7) * 8;          // k-col chunk (8 elems)
    const int sRowB = lane >> 3;           // 0..7 (row within 8-row chunk)
    const int sColB = (lane & 7) * 8;      // k-col chunk
    f32x4 plo[4], phi[4];
    #pragma unroll
    for (int p = 0; p < 4; ++p) {
      const float* s = gA32 + (size_t)(p * 32 + rA) * K + cA;
      plo[p] = *(const f32x4*)(s);  phi[p] = *(const f32x4*)(s + 4);
    }

    #pragma unroll 1
    for (int kt = 0; kt < K; kt += 64) {
      __syncthreads();
      // pack + write A(t) (values loaded during the previous MFMA phase)
      #pragma unroll
      for (int p = 0; p < 4; ++p) {
        u32x4 w;
        w[0] = pk_bf16(plo[p][0], plo[p][1]); w[1] = pk_bf16(plo[p][2], plo[p][3]);
        w[2] = pk_bf16(phi[p][0], phi[p][1]); w[3] = pk_bf16(phi[p][2], phi[p][3]);
        *(u32x4*)(As + (p * 32 + rA) * 64 + cA) = w;
      }
      // stage B(t): 16 chunks x 1KB, rows ci*8..ci*8+7 of [128][64]
      #pragma unroll
      for (int r = 0; r < 4; ++r) {
        int ci = r * 4 + wid;
        gload_lds16(gB + (size_t)(ci * 8 + sRowB) * K + kt + sColB, (char*)Bs + ci * 1024);
      }
      __syncthreads();

      if (kt + 64 < K) {   // issue-early: next A loads fly under the MFMAs below
        #pragma unroll
        for (int p = 0; p < 4; ++p) {
          const float* s = gA32 + (size_t)(p * 32 + rA) * K + kt + 64 + cA;
          plo[p] = *(const f32x4*)(s);  phi[p] = *(const f32x4*)(s + 4);
        }
      }

      #pragma unroll
      for (int kk = 0; kk < 2; ++kk) {
        short8 a[4], b[4];
        #pragma unroll
        for (int m = 0; m < 4; ++m)
          a[m] = *(const short8*)(As + (wr * 64 + m * 16 + fr) * 64 + kk * 32 + fq * 8);
        #pragma unroll
        for (int n = 0; n < 4; ++n)
          b[n] = *(const short8*)(Bs + (wc * 64 + n * 16 + fr) * 64 + kk * 32 + fq * 8);
        #pragma unroll
        for (int m = 0; m < 4; ++m)
          #pragma unroll
          for (int n = 0; n < 4; ++n)
            acc[m][n] = __builtin_amdgcn_mfma_f32_16x16x32_bf16(a[m], b[n], acc[m][n], 0, 0, 0);
      }
    }
  } else {
    // -------- BK=32 bf16 path (final GEMM) --------
    for (int kt = 0; kt < K; kt += 32) {
      __syncthreads();
      #pragma unroll
      for (int r = 0; r < 2; ++r) {
        int ci = r * 4 + wid;
        gload_lds16(gA16 + (size_t)(ci * 16 + sRow) * K + kt + sCol, (char*)As + ci * 1024);
        gload_lds16(gB   + (size_t)(ci * 16 + sRow) * K + kt + sCol, (char*)Bs + ci * 1024);
      }
      __syncthreads();

      short8 a[4], b[4];
      #pragma unroll
      for (int m = 0; m < 4; ++m)
        a[m] = *(const short8*)(As + (wr * 64 + m * 16 + fr) * 32 + fq * 8);
      #pragma unroll
      for (int n = 0; n < 4; ++n)
        b[n] = *(const short8*)(Bs + (wc * 64 + n * 16 + fr) * 32 + fq * 8);
      #pragma unroll
      for (int m = 0; m < 4; ++m)
        #pragma unroll
        for (int n = 0; n < 4; ++n)
          acc[m][n] = __builtin_amdgcn_mfma_f32_16x16x32_bf16(a[m], b[n], acc[m][n], 0, 0, 0);
    }
  }

  const float* bias = QKV3 ? (sel == 0 ? b0 : sel == 1 ? b1 : b2) : b0;
  const float os = (QKV3 && sel != 0) ? 1.0f : oscale;
  u16* dst16 = (u16*)Cout + (QKV3 ? (size_t)sel * MM * DD : 0);

  const int rowBase = mt * 128 + wr * 64;
  const int colBase = nt * 128 + wc * 64;
  #pragma unroll
  for (int n = 0; n < 4; ++n) {
    int col = colBase + n * 16 + fr;
    float bi = bias[col];
    #pragma unroll
    for (int m = 0; m < 4; ++m) {
      #pragma unroll
      for (int r2 = 0; r2 < 4; ++r2) {
        int row = rowBase + m * 16 + fq * 4 + r2;
        float v = (acc[m][n][r2] + bi) * os;
        if (BF16OUT) dst16[(size_t)row * N + col] = f2bf(v);
        else         ((float*)Cout)[(size_t)row * N + col] = v;
      }
    }
  }
}

// ---- flash attention, swapped-QK^T, 32x32x16 MFMA, static-max softmax ----
// R16 kernel (validated): R3 structure + per-kvb interleaved COMPUTE,
// __launch_bounds__(256,2). (256,3) is RETIRED — R10 miscompiled under that cap.
__global__ __launch_bounds__(256, 2) void attn_kernel(const u16* __restrict__ Qb,
                                                      const u16* __restrict__ Kb,
                                                      const u16* __restrict__ Vtg,
                                                      u16* __restrict__ Ob) {
  __shared__ __align__(16) u16 Ks[2][64 * 64];   // [kv][d], swizzled
  __shared__ __align__(16) u16 Vts[2][64 * 64];  // [d][kv], swizzled
  __shared__ float sbuf[4][2][32];

  const int tid = threadIdx.x, lane = tid & 63, wid = tid >> 6;
  const int l31 = lane & 31, hi = lane >> 5;
  const int bh = blockIdx.x, qt = blockIdx.y;
  const int b = bh >> 4, h = bh & 15;
  const size_t hb = (size_t)b * SS * DD + h * 64;
  const int swz = (lane & 7) << 4;                        // read-side XOR (bytes)
  const int lslot8 = ((lane & 7) ^ (lane >> 3)) * 8;      // stage source slot (elems)
  const int srow = lane >> 3;

  // Q fragments (B operand): col q = l31, k = d = c*16 + hi*8 + j
  const int qrow0 = qt * 256 + wid * 64;
  short8 qf[2][4];
  #pragma unroll
  for (int qb = 0; qb < 2; ++qb)
    #pragma unroll
    for (int c = 0; c < 4; ++c)
      qf[qb][c] = *(const short8*)(Qb + hb + (size_t)(qrow0 + qb * 32 + l31) * DD + c * 16 + hi * 8);

  f32x16 Oa[2][2];
  #pragma unroll
  for (int qb = 0; qb < 2; ++qb)
    #pragma unroll
    for (int dblk = 0; dblk < 2; ++dblk) Oa[qb][dblk] = (f32x16)0.0f;
  float lrow[2] = {0.0f, 0.0f};

  // staging base pointers (incremental, uniform k-tile stride)
  const u16* kS = Kb + hb + (size_t)(wid * 16 + srow) * DD + lslot8;
  const u16* vS = Vtg + ((size_t)bh * 64 + wid * 16 + srow) * SS + lslot8;
  char* kD = (char*)Ks[0] + wid * 2048;
  char* vD = (char*)Vts[0] + wid * 2048;

  auto STAGE = [&](int t, int b2) {
    gload_lds16(kS + (size_t)t * 64 * DD,          kD + b2 * 8192);
    gload_lds16(kS + (size_t)t * 64 * DD + 8 * DD, kD + b2 * 8192 + 1024);
    gload_lds16(vS + t * 64,                       vD + b2 * 8192);
    gload_lds16(vS + t * 64 + 8 * SS,              vD + b2 * 8192 + 1024);
  };

  auto COMPUTE = [&](int b2) {
    const char* Kt = (const char*)Ks[b2];
    const char* Vt = (const char*)Vts[b2];
    short8 PA[2][4];
    float ls[2] = {0.0f, 0.0f};

    // interleaved per-kvb: QK MFMA -> exp2 -> pack, one 32-kv half at a time
    #pragma unroll
    for (int kvb = 0; kvb < 2; ++kvb) {
      short8 kf[4];
      #pragma unroll
      for (int c = 0; c < 4; ++c)
        kf[c] = *(const short8*)(Kt + (kvb * 32 + l31) * 128 + ((c * 32 + hi * 16) ^ swz));
      #pragma unroll
      for (int qb = 0; qb < 2; ++qb) {
        f32x16 s = (f32x16)0.0f;
        __builtin_amdgcn_s_setprio(1);
        #pragma unroll
        for (int c = 0; c < 4; ++c)
          s = __builtin_amdgcn_mfma_f32_32x32x16_bf16(kf[c], qf[qb][c], s, 0, 0, 0);
        __builtin_amdgcn_s_setprio(0);
        // s[r] = S^T[kv = kvb*32 + (r&3)+8*(r>>2)+4*hi][q = qrow0 + qb*32 + l31]

        float p[16];
        #pragma unroll
        for (int r = 0; r < 16; ++r) p[r] = ex2(s[r]);

        float t8[8];
        #pragma unroll
        for (int i = 0; i < 8; ++i) t8[i] = p[2 * i] + p[2 * i + 1];
        ls[qb] += ((t8[0] + t8[1]) + (t8[2] + t8[3])) + ((t8[4] + t8[5]) + (t8[6] + t8[7]));

        // redistribute to PV A-frag layout via cvt_pk + half-swap
        unsigned w0, w1, w2, w3;
        unsigned A0 = pk_bf16(p[0], p[1]),   A1 = pk_bf16(p[2], p[3]);
        unsigned B0 = pk_bf16(p[4], p[5]),   B1 = pk_bf16(p[6], p[7]);
        swap_half(A0, B0, w0, w2); swap_half(A1, B1, w1, w3);
        u32x4 t0; t0[0] = w0; t0[1] = w1; t0[2] = w2; t0[3] = w3;
        PA[qb][kvb * 2] = __builtin_bit_cast(short8, t0);
        unsigned C0 = pk_bf16(p[8], p[9]),   C1 = pk_bf16(p[10], p[11]);
        unsigned D0 = pk_bf16(p[12], p[13]), D1 = pk_bf16(p[14], p[15]);
        swap_half(C0, D0, w0, w2); swap_half(C1, D1, w1, w3);
        u32x4 t1; t1[0] = w0; t1[1] = w1; t1[2] = w2; t1[3] = w3;
        PA[qb][kvb * 2 + 1] = __builtin_bit_cast(short8, t1);
      }
    }
    #pragma unroll
    for (int qb = 0; qb < 2; ++qb)
      lrow[qb] += ls[qb] + xchg_half(ls[qb]);

    // PV: A = P frags, B = V^T rows (row d = dblk*32 + l31, k = kv)
    __builtin_amdgcn_s_setprio(1);
    #pragma unroll
    for (int dblk = 0; dblk < 2; ++dblk)
      #pragma unroll
      for (int kvc = 0; kvc < 4; ++kvc) {
        short8 vf = *(const short8*)(Vt + (dblk * 32 + l31) * 128 + ((kvc * 32 + hi * 16) ^ swz));
        Oa[0][dblk] = __builtin_amdgcn_mfma_f32_32x32x16_bf16(PA[0][kvc], vf, Oa[0][dblk], 0, 0, 0);
        Oa[1][dblk] = __builtin_amdgcn_mfma_f32_32x32x16_bf16(PA[1][kvc], vf, Oa[1][dblk], 0, 0, 0);
      }
    __builtin_amdgcn_s_setprio(0);
  };

  STAGE(0, 0);
  __syncthreads();

  #pragma unroll 1
  for (int kt = 0; kt < SS / 64; kt += 2) {
    STAGE(kt + 1, 1);
    COMPUTE(0);
    __syncthreads();
    if (kt + 2 < SS / 64) STAGE(kt + 2, 0);
    COMPUTE(1);
    __syncthreads();
  }

  // epilogue: redistribute 1/l per q-row via per-wave LDS (same-wave, no barrier)
  #pragma unroll
  for (int qb = 0; qb < 2; ++qb)
    if (!hi) sbuf[wid][qb][l31] = 1.0f / lrow[qb];
  #pragma unroll
  for (int qb = 0; qb < 2; ++qb)
    #pragma unroll
    for (int r = 0; r < 16; ++r) {
      float inv = sbuf[wid][qb][(r & 3) + 8 * (r >> 2) + 4 * hi];
      int qrow = qrow0 + qb * 32 + (r & 3) + 8 * (r >> 2) + 4 * hi;
      size_t orow = (size_t)(b * SS + qrow) * DD + h * 64;
      Ob[orow + l31]      = f2bf(Oa[qb][0][r] * inv);
      Ob[orow + 32 + l31] = f2bf(Oa[qb][1][r] * inv);
    }
}

extern "C" void kernel_launch(void* const* d_in, const int* in_sizes, int n_in,
                              void* d_out, int out_size, void* d_ws, size_t ws_size,
                              hipStream_t stream) {
  const float* q  = (const float*)d_in[0];
  const float* k  = (const float*)d_in[1];
  const float* v  = (const float*)d_in[2];
  const float* Wq = (const float*)d_in[3];
  const float* bq = (const float*)d_in[4];
  const float* Wk = (const float*)d_in[5];
  const float* bk = (const float*)d_in[6];
  const float* Wv = (const float*)d_in[7];
  const float* bv = (const float*)d_in[8];
  const float* Wo = (const float*)d_in[9];
  const float* bo = (const float*)d_in[10];
  float* out = (float*)d_out;

  u16* WT   = (u16*)d_ws;                  // 4 x DD*DD bf16 (Wq,Wk,Wv,Wo transposed)
  u16* Qb   = WT + (size_t)4 * DD * DD;    // Qb,Kb,Vb contiguous (fused epilogue)
  u16* Kb   = Qb + (size_t)MM * DD;
  u16* Vb   = Kb + (size_t)MM * DD;
  u16* Vtg  = Vb + (size_t)MM * DD;        // per-(b,h) V^T panels [bh*64+d][SS]
  u16* AOut = Vb;                          // V rows dead after vtrans

  wtrans4_kernel<<<dim3(32, 32, 4), dim3(32, 8), 0, stream>>>(Wq, Wk, Wv, Wo, WT);

  // Fused QKV projection: reg-staged fp32 A, issue-early, BK=64.
  gemm_bt<2, 1, 1><<<dim3(MM / 128, 24), 256, 0, stream>>>(
      q, k, v, WT, bq, bk, bv, Qb, SLOG2E, MM, DD, DD);

  vtrans_kernel<<<dim3(64, 32), 256, 0, stream>>>(Vb, Vtg);
  attn_kernel<<<dim3(64, 8), 256, 0, stream>>>(Qb, Kb, Vtg, AOut);
  gemm_bt<0, 0, 0><<<dim3(MM / 128, DD / 128), 256, 0, stream>>>(
      AOut, nullptr, nullptr, WT + (size_t)3 * DD * DD, bo, nullptr, nullptr, out, 1.0f, MM, DD, DD);
}

// Round 25
// 190.333 us; speedup vs baseline: 1.0988x; 1.0988x over previous
//
#include <hip/hip_runtime.h>

// ---- problem constants ----
#define BB 4
#define SS 2048
#define DD 1024
#define HH 16
#define MM (BB*SS)          // 8192
#define SLOG2E 0.1803368801111204f   // 0.125 * log2(e): folded into Q projection

typedef __attribute__((ext_vector_type(4))) float f32x4;
typedef __attribute__((ext_vector_type(16))) float f32x16;
typedef __attribute__((ext_vector_type(8))) short short8;
typedef __attribute__((ext_vector_type(4))) unsigned int u32x4;
typedef unsigned short u16;

__device__ __forceinline__ u16 f2bf(float f) {
  unsigned int u = __float_as_uint(f);
  u += 0x7FFF + ((u >> 16) & 1);   // RNE
  return (u16)(u >> 16);
}

__device__ __forceinline__ void gload_lds16(const void* g, void* l) {
  __builtin_amdgcn_global_load_lds(
      (__attribute__((address_space(1))) void*)(g),
      (__attribute__((address_space(3))) void*)(l),
      16, 0, 0);
}

__device__ __forceinline__ unsigned pk_bf16(float lo, float hi) {
  unsigned r;
  asm("v_cvt_pk_bf16_f32 %0, %1, %2" : "=v"(r) : "v"(lo), "v"(hi));
  return r;
}

__device__ __forceinline__ float ex2(float x) {
#if __has_builtin(__builtin_amdgcn_exp2f)
  return __builtin_amdgcn_exp2f(x);
#else
  return exp2f(x);
#endif
}

// swap_half(a,b) -> x = {a.lo32, b.lo32}, y = {a.hi32, b.hi32}
__device__ __forceinline__ void swap_half(unsigned a, unsigned b, unsigned& x, unsigned& y) {
#if __has_builtin(__builtin_amdgcn_permlane32_swap)
  auto r = __builtin_amdgcn_permlane32_swap(a, b, false, false);
  x = r[0]; y = r[1];
#else
  unsigned ax = (unsigned)__shfl_xor((int)a, 32, 64);
  unsigned bx = (unsigned)__shfl_xor((int)b, 32, 64);
  bool hb = (threadIdx.x & 32) != 0;
  x = hb ? bx : a;
  y = hb ? b : ax;
#endif
}

__device__ __forceinline__ float xchg_half(float v) {
  unsigned x, y;
  swap_half(__float_as_uint(v), __float_as_uint(v), x, y);
  return __uint_as_float((threadIdx.x & 32) ? x : y);
}

// ---- all 4 weight transposes in one launch: W [K][N] fp32 -> WT [N][K] bf16 ----
__global__ __launch_bounds__(256) void wtrans4_kernel(const float* __restrict__ Wq,
                                                      const float* __restrict__ Wk,
                                                      const float* __restrict__ Wv,
                                                      const float* __restrict__ Wo,
                                                      u16* __restrict__ WT) {
  const int z = blockIdx.z;
  const float* W = (z == 0) ? Wq : (z == 1) ? Wk : (z == 2) ? Wv : Wo;
  u16* dst = WT + (size_t)z * DD * DD;
  __shared__ float t[32][33];
  int n0 = blockIdx.x * 32, k0 = blockIdx.y * 32;
  int tx = threadIdx.x, ty = threadIdx.y;  // 32 x 8
  #pragma unroll
  for (int r = 0; r < 32; r += 8) t[r + ty][tx] = W[(size_t)(k0 + r + ty) * DD + n0 + tx];
  __syncthreads();
  #pragma unroll
  for (int r = 0; r < 32; r += 8) dst[(size_t)(n0 + r + ty) * DD + k0 + tx] = f2bf(t[tx][r + ty]);
}

// ---- V [M][D] bf16 -> per-head V^T : Vtg[(bh*64 + d)*SS + s] ----
__global__ __launch_bounds__(256) void vtrans_kernel(const u16* __restrict__ Vb,
                                                     u16* __restrict__ Vtg) {
  __shared__ u16 T[64][72];
  int bh = blockIdx.x, st = blockIdx.y;
  int b = bh >> 4, h = bh & 15;
  const u16* src = Vb + ((size_t)(b * SS + st * 64)) * DD + h * 64;
  int r = threadIdx.x >> 3;        // 0..31
  int s8 = threadIdx.x & 7;
  #pragma unroll
  for (int half = 0; half < 2; ++half) {
    int row = half * 32 + r;
    short8 vv = *(const short8*)(src + (size_t)row * DD + s8 * 8);
    #pragma unroll
    for (int j = 0; j < 8; ++j) T[row][s8 * 8 + j] = (u16)vv[j];
  }
  __syncthreads();
  u16* dst = Vtg + ((size_t)bh * 64) * SS + st * 64;
  #pragma unroll
  for (int half = 0; half < 2; ++half) {
    int d = half * 32 + r;
    short8 ov;
    #pragma unroll
    for (int j = 0; j < 8; ++j) ov[j] = (short)T[s8 * 8 + j][d];
    *(short8*)(dst + (size_t)d * SS + s8 * 8) = ov;
  }
}

// ---- GEMM: C[M][N] = A[M][K] * Bt[N][K]^T + bias, fp32 acc ----
// AMODE 0: A bf16 in global, gload_lds staging, BK=32 (m97 path).
// AMODE 2: A fp32, reg-staged with T14 issue-early pipeline (R18-validated:
//   QKV 125->111us), BK=32. All alternatives measured worse: B dbuf (R19 +8,
//   R21 +40 via occupancy loss), BK=64 (R24 +12: occupancy 30->20%, conflicts
//   3x). B stays single-buffered; compiler schedules the 2-barrier loop best.
// QKV3: fused QKV projection — blockIdx.y in [0,24): sel = y>>3 picks the input
// tensor {q,k,v}, weight panel, bias, output buffer; sel 0 scaled by oscale.
template <int AMODE, int BF16OUT, int QKV3>
__global__ __launch_bounds__(256) void gemm_bt(const void* __restrict__ Ap0, const void* __restrict__ Ap1,
                                               const void* __restrict__ Ap2, const u16* __restrict__ Bt,
                                               const float* __restrict__ b0, const float* __restrict__ b1,
                                               const float* __restrict__ b2, void* __restrict__ Cout,
                                               float oscale, int M, int N, int K) {
  __shared__ __align__(16) u16 As[128 * 32];
  __shared__ __align__(16) u16 Bs[128 * 32];
  const int tid = threadIdx.x, lane = tid & 63, wid = tid >> 6;
  const int wr = wid >> 1, wc = wid & 1;
  const int fr = lane & 15, fq = lane >> 4;
  const int mt = blockIdx.x;
  const int ntg = blockIdx.y;
  const int sel = QKV3 ? (ntg >> 3) : 0;
  const int nt = QKV3 ? (ntg & 7) : ntg;
  const void* Ap = QKV3 ? (sel == 0 ? Ap0 : sel == 1 ? Ap1 : Ap2) : Ap0;

  f32x4 acc[4][4];
  #pragma unroll
  for (int m = 0; m < 4; ++m)
    #pragma unroll
    for (int n = 0; n < 4; ++n) acc[m][n] = (f32x4)0.0f;

  const int sRow = lane >> 2;              // bf16 staging: 16 rows/KB chunk
  const int sCol = (lane & 3) * 8;

  const float* gA32 = (const float*)Ap + (size_t)(mt * 128) * K;
  const u16*   gA16 = (const u16*)Ap + (size_t)(mt * 128) * K;
  const u16*   gB   = Bt + (QKV3 ? (size_t)sel * DD * DD : 0) + (size_t)(nt * 128) * K;

  // AMODE==2 pipeline registers (rows rA and rA+64, same column)
  const int rA = tid >> 2;
  const int cA = (tid & 3) * 8;
  f32x4 p0lo, p0hi, p1lo, p1hi;
  if (AMODE == 2) {
    const float* s0 = gA32 + (size_t)rA * K + cA;
    const float* s1 = gA32 + (size_t)(rA + 64) * K + cA;
    p0lo = *(const f32x4*)(s0);     p0hi = *(const f32x4*)(s0 + 4);
    p1lo = *(const f32x4*)(s1);     p1hi = *(const f32x4*)(s1 + 4);
  }

  for (int kt = 0; kt < K; kt += 32) {
    __syncthreads();
    if (AMODE == 2) {
      // pack + write the values loaded during the PREVIOUS iteration's MFMA phase
      u32x4 w;
      w[0] = pk_bf16(p0lo[0], p0lo[1]); w[1] = pk_bf16(p0lo[2], p0lo[3]);
      w[2] = pk_bf16(p0hi[0], p0hi[1]); w[3] = pk_bf16(p0hi[2], p0hi[3]);
      *(u32x4*)(As + rA * 32 + cA) = w;
      w[0] = pk_bf16(p1lo[0], p1lo[1]); w[1] = pk_bf16(p1lo[2], p1lo[3]);
      w[2] = pk_bf16(p1hi[0], p1hi[1]); w[3] = pk_bf16(p1hi[2], p1hi[3]);
      *(u32x4*)(As + (rA + 64) * 32 + cA) = w;
    } else {
      #pragma unroll
      for (int r = 0; r < 2; ++r) {
        int ci = r * 4 + wid;
        gload_lds16(gA16 + (size_t)(ci * 16 + sRow) * K + kt + sCol, (char*)As + ci * 1024);
      }
    }
    #pragma unroll
    for (int r = 0; r < 2; ++r) {
      int ci = r * 4 + wid;
      gload_lds16(gB + (size_t)(ci * 16 + sRow) * K + kt + sCol, (char*)Bs + ci * 1024);
    }
    __syncthreads();

    if (AMODE == 2 && kt + 32 < K) {
      // issue-early: next step's A loads fly under the MFMA phase below
      const float* s0 = gA32 + (size_t)rA * K + kt + 32 + cA;
      const float* s1 = gA32 + (size_t)(rA + 64) * K + kt + 32 + cA;
      p0lo = *(const f32x4*)(s0);     p0hi = *(const f32x4*)(s0 + 4);
      p1lo = *(const f32x4*)(s1);     p1hi = *(const f32x4*)(s1 + 4);
    }

    short8 a[4], b[4];
    #pragma unroll
    for (int m = 0; m < 4; ++m)
      a[m] = *(const short8*)(As + (wr * 64 + m * 16 + fr) * 32 + fq * 8);
    #pragma unroll
    for (int n = 0; n < 4; ++n)
      b[n] = *(const short8*)(Bs + (wc * 64 + n * 16 + fr) * 32 + fq * 8);
    #pragma unroll
    for (int m = 0; m < 4; ++m)
      #pragma unroll
      for (int n = 0; n < 4; ++n)
        acc[m][n] = __builtin_amdgcn_mfma_f32_16x16x32_bf16(a[m], b[n], acc[m][n], 0, 0, 0);
  }

  const float* bias = QKV3 ? (sel == 0 ? b0 : sel == 1 ? b1 : b2) : b0;
  const float os = (QKV3 && sel != 0) ? 1.0f : oscale;
  u16* dst16 = (u16*)Cout + (QKV3 ? (size_t)sel * MM * DD : 0);

  const int rowBase = mt * 128 + wr * 64;
  const int colBase = nt * 128 + wc * 64;
  #pragma unroll
  for (int n = 0; n < 4; ++n) {
    int col = colBase + n * 16 + fr;
    float bi = bias[col];
    #pragma unroll
    for (int m = 0; m < 4; ++m) {
      #pragma unroll
      for (int r2 = 0; r2 < 4; ++r2) {
        int row = rowBase + m * 16 + fq * 4 + r2;
        float v = (acc[m][n][r2] + bi) * os;
        if (BF16OUT) dst16[(size_t)row * N + col] = f2bf(v);
        else         ((float*)Cout)[(size_t)row * N + col] = v;
      }
    }
  }
}

// ---- flash attention, swapped-QK^T, 32x32x16 MFMA, static-max softmax ----
// R16 kernel (validated): R3 structure + per-kvb interleaved COMPUTE,
// __launch_bounds__(256,2). (256,3) is RETIRED — R10 miscompiled under that cap.
__global__ __launch_bounds__(256, 2) void attn_kernel(const u16* __restrict__ Qb,
                                                      const u16* __restrict__ Kb,
                                                      const u16* __restrict__ Vtg,
                                                      u16* __restrict__ Ob) {
  __shared__ __align__(16) u16 Ks[2][64 * 64];   // [kv][d], swizzled
  __shared__ __align__(16) u16 Vts[2][64 * 64];  // [d][kv], swizzled
  __shared__ float sbuf[4][2][32];

  const int tid = threadIdx.x, lane = tid & 63, wid = tid >> 6;
  const int l31 = lane & 31, hi = lane >> 5;
  const int bh = blockIdx.x, qt = blockIdx.y;
  const int b = bh >> 4, h = bh & 15;
  const size_t hb = (size_t)b * SS * DD + h * 64;
  const int swz = (lane & 7) << 4;                        // read-side XOR (bytes)
  const int lslot8 = ((lane & 7) ^ (lane >> 3)) * 8;      // stage source slot (elems)
  const int srow = lane >> 3;

  // Q fragments (B operand): col q = l31, k = d = c*16 + hi*8 + j
  const int qrow0 = qt * 256 + wid * 64;
  short8 qf[2][4];
  #pragma unroll
  for (int qb = 0; qb < 2; ++qb)
    #pragma unroll
    for (int c = 0; c < 4; ++c)
      qf[qb][c] = *(const short8*)(Qb + hb + (size_t)(qrow0 + qb * 32 + l31) * DD + c * 16 + hi * 8);

  f32x16 Oa[2][2];
  #pragma unroll
  for (int qb = 0; qb < 2; ++qb)
    #pragma unroll
    for (int dblk = 0; dblk < 2; ++dblk) Oa[qb][dblk] = (f32x16)0.0f;
  float lrow[2] = {0.0f, 0.0f};

  // staging base pointers (incremental, uniform k-tile stride)
  const u16* kS = Kb + hb + (size_t)(wid * 16 + srow) * DD + lslot8;
  const u16* vS = Vtg + ((size_t)bh * 64 + wid * 16 + srow) * SS + lslot8;
  char* kD = (char*)Ks[0] + wid * 2048;
  char* vD = (char*)Vts[0] + wid * 2048;

  auto STAGE = [&](int t, int b2) {
    gload_lds16(kS + (size_t)t * 64 * DD,          kD + b2 * 8192);
    gload_lds16(kS + (size_t)t * 64 * DD + 8 * DD, kD + b2 * 8192 + 1024);
    gload_lds16(vS + t * 64,                       vD + b2 * 8192);
    gload_lds16(vS + t * 64 + 8 * SS,              vD + b2 * 8192 + 1024);
  };

  auto COMPUTE = [&](int b2) {
    const char* Kt = (const char*)Ks[b2];
    const char* Vt = (const char*)Vts[b2];
    short8 PA[2][4];
    float ls[2] = {0.0f, 0.0f};

    // interleaved per-kvb: QK MFMA -> exp2 -> pack, one 32-kv half at a time
    #pragma unroll
    for (int kvb = 0; kvb < 2; ++kvb) {
      short8 kf[4];
      #pragma unroll
      for (int c = 0; c < 4; ++c)
        kf[c] = *(const short8*)(Kt + (kvb * 32 + l31) * 128 + ((c * 32 + hi * 16) ^ swz));
      #pragma unroll
      for (int qb = 0; qb < 2; ++qb) {
        f32x16 s = (f32x16)0.0f;
        __builtin_amdgcn_s_setprio(1);
        #pragma unroll
        for (int c = 0; c < 4; ++c)
          s = __builtin_amdgcn_mfma_f32_32x32x16_bf16(kf[c], qf[qb][c], s, 0, 0, 0);
        __builtin_amdgcn_s_setprio(0);
        // s[r] = S^T[kv = kvb*32 + (r&3)+8*(r>>2)+4*hi][q = qrow0 + qb*32 + l31]

        float p[16];
        #pragma unroll
        for (int r = 0; r < 16; ++r) p[r] = ex2(s[r]);

        float t8[8];
        #pragma unroll
        for (int i = 0; i < 8; ++i) t8[i] = p[2 * i] + p[2 * i + 1];
        ls[qb] += ((t8[0] + t8[1]) + (t8[2] + t8[3])) + ((t8[4] + t8[5]) + (t8[6] + t8[7]));

        // redistribute to PV A-frag layout via cvt_pk + half-swap
        unsigned w0, w1, w2, w3;
        unsigned A0 = pk_bf16(p[0], p[1]),   A1 = pk_bf16(p[2], p[3]);
        unsigned B0 = pk_bf16(p[4], p[5]),   B1 = pk_bf16(p[6], p[7]);
        swap_half(A0, B0, w0, w2); swap_half(A1, B1, w1, w3);
        u32x4 t0; t0[0] = w0; t0[1] = w1; t0[2] = w2; t0[3] = w3;
        PA[qb][kvb * 2] = __builtin_bit_cast(short8, t0);
        unsigned C0 = pk_bf16(p[8], p[9]),   C1 = pk_bf16(p[10], p[11]);
        unsigned D0 = pk_bf16(p[12], p[13]), D1 = pk_bf16(p[14], p[15]);
        swap_half(C0, D0, w0, w2); swap_half(C1, D1, w1, w3);
        u32x4 t1; t1[0] = w0; t1[1] = w1; t1[2] = w2; t1[3] = w3;
        PA[qb][kvb * 2 + 1] = __builtin_bit_cast(short8, t1);
      }
    }
    #pragma unroll
    for (int qb = 0; qb < 2; ++qb)
      lrow[qb] += ls[qb] + xchg_half(ls[qb]);

    // PV: A = P frags, B = V^T rows (row d = dblk*32 + l31, k = kv)
    __builtin_amdgcn_s_setprio(1);
    #pragma unroll
    for (int dblk = 0; dblk < 2; ++dblk)
      #pragma unroll
      for (int kvc = 0; kvc < 4; ++kvc) {
        short8 vf = *(const short8*)(Vt + (dblk * 32 + l31) * 128 + ((kvc * 32 + hi * 16) ^ swz));
        Oa[0][dblk] = __builtin_amdgcn_mfma_f32_32x32x16_bf16(PA[0][kvc], vf, Oa[0][dblk], 0, 0, 0);
        Oa[1][dblk] = __builtin_amdgcn_mfma_f32_32x32x16_bf16(PA[1][kvc], vf, Oa[1][dblk], 0, 0, 0);
      }
    __builtin_amdgcn_s_setprio(0);
  };

  STAGE(0, 0);
  __syncthreads();

  #pragma unroll 1
  for (int kt = 0; kt < SS / 64; kt += 2) {
    STAGE(kt + 1, 1);
    COMPUTE(0);
    __syncthreads();
    if (kt + 2 < SS / 64) STAGE(kt + 2, 0);
    COMPUTE(1);
    __syncthreads();
  }

  // epilogue: redistribute 1/l per q-row via per-wave LDS (same-wave, no barrier)
  #pragma unroll
  for (int qb = 0; qb < 2; ++qb)
    if (!hi) sbuf[wid][qb][l31] = 1.0f / lrow[qb];
  #pragma unroll
  for (int qb = 0; qb < 2; ++qb)
    #pragma unroll
    for (int r = 0; r < 16; ++r) {
      float inv = sbuf[wid][qb][(r & 3) + 8 * (r >> 2) + 4 * hi];
      int qrow = qrow0 + qb * 32 + (r & 3) + 8 * (r >> 2) + 4 * hi;
      size_t orow = (size_t)(b * SS + qrow) * DD + h * 64;
      Ob[orow + l31]      = f2bf(Oa[qb][0][r] * inv);
      Ob[orow + 32 + l31] = f2bf(Oa[qb][1][r] * inv);
    }
}

extern "C" void kernel_launch(void* const* d_in, const int* in_sizes, int n_in,
                              void* d_out, int out_size, void* d_ws, size_t ws_size,
                              hipStream_t stream) {
  const float* q  = (const float*)d_in[0];
  const float* k  = (const float*)d_in[1];
  const float* v  = (const float*)d_in[2];
  const float* Wq = (const float*)d_in[3];
  const float* bq = (const float*)d_in[4];
  const float* Wk = (const float*)d_in[5];
  const float* bk = (const float*)d_in[6];
  const float* Wv = (const float*)d_in[7];
  const float* bv = (const float*)d_in[8];
  const float* Wo = (const float*)d_in[9];
  const float* bo = (const float*)d_in[10];
  float* out = (float*)d_out;

  u16* WT   = (u16*)d_ws;                  // 4 x DD*DD bf16 (Wq,Wk,Wv,Wo transposed)
  u16* Qb   = WT + (size_t)4 * DD * DD;    // Qb,Kb,Vb contiguous (fused epilogue)
  u16* Kb   = Qb + (size_t)MM * DD;
  u16* Vb   = Kb + (size_t)MM * DD;
  u16* Vtg  = Vb + (size_t)MM * DD;        // per-(b,h) V^T panels [bh*64+d][SS]
  u16* AOut = Vb;                          // V rows dead after vtrans

  wtrans4_kernel<<<dim3(32, 32, 4), dim3(32, 8), 0, stream>>>(Wq, Wk, Wv, Wo, WT);

  // Fused QKV projection, reg-staged fp32 A with issue-early pipeline (AMODE=2).
  gemm_bt<2, 1, 1><<<dim3(MM / 128, 24), 256, 0, stream>>>(
      q, k, v, WT, bq, bk, bv, Qb, SLOG2E, MM, DD, DD);

  vtrans_kernel<<<dim3(64, 32), 256, 0, stream>>>(Vb, Vtg);
  attn_kernel<<<dim3(64, 8), 256, 0, stream>>>(Qb, Kb, Vtg, AOut);
  gemm_bt<0, 0, 0><<<dim3(MM / 128, DD / 128), 256, 0, stream>>>(
      AOut, nullptr, nullptr, WT + (size_t)3 * DD * DD, bo, nullptr, nullptr, out, 1.0f, MM, DD, DD);
}

// Round 26
// 189.532 us; speedup vs baseline: 1.1035x; 1.0042x over previous
//
#include <hip/hip_runtime.h>

// ---- problem constants ----
#define BB 4
#define SS 2048
#define DD 1024
#define HH 16
#define MM (BB*SS)          // 8192
#define SLOG2E 0.1803368801111204f   // 0.125 * log2(e): folded into Q projection

typedef __attribute__((ext_vector_type(4))) float f32x4;
typedef __attribute__((ext_vector_type(16))) float f32x16;
typedef __attribute__((ext_vector_type(8))) short short8;
typedef __attribute__((ext_vector_type(4))) unsigned int u32x4;
typedef unsigned short u16;

__device__ __forceinline__ u16 f2bf(float f) {
  unsigned int u = __float_as_uint(f);
  u += 0x7FFF + ((u >> 16) & 1);   // RNE
  return (u16)(u >> 16);
}

__device__ __forceinline__ void gload_lds16(const void* g, void* l) {
  __builtin_amdgcn_global_load_lds(
      (__attribute__((address_space(1))) void*)(g),
      (__attribute__((address_space(3))) void*)(l),
      16, 0, 0);
}

__device__ __forceinline__ unsigned pk_bf16(float lo, float hi) {
  unsigned r;
  asm("v_cvt_pk_bf16_f32 %0, %1, %2" : "=v"(r) : "v"(lo), "v"(hi));
  return r;
}

__device__ __forceinline__ float ex2(float x) {
#if __has_builtin(__builtin_amdgcn_exp2f)
  return __builtin_amdgcn_exp2f(x);
#else
  return exp2f(x);
#endif
}

// swap_half(a,b) -> x = {a.lo32, b.lo32}, y = {a.hi32, b.hi32}
__device__ __forceinline__ void swap_half(unsigned a, unsigned b, unsigned& x, unsigned& y) {
#if __has_builtin(__builtin_amdgcn_permlane32_swap)
  auto r = __builtin_amdgcn_permlane32_swap(a, b, false, false);
  x = r[0]; y = r[1];
#else
  unsigned ax = (unsigned)__shfl_xor((int)a, 32, 64);
  unsigned bx = (unsigned)__shfl_xor((int)b, 32, 64);
  bool hb = (threadIdx.x & 32) != 0;
  x = hb ? bx : a;
  y = hb ? b : ax;
#endif
}

__device__ __forceinline__ float xchg_half(float v) {
  unsigned x, y;
  swap_half(__float_as_uint(v), __float_as_uint(v), x, y);
  return __uint_as_float((threadIdx.x & 32) ? x : y);
}

// ---- all 4 weight transposes in one launch: W [K][N] fp32 -> WT [N][K] bf16 ----
__global__ __launch_bounds__(256) void wtrans4_kernel(const float* __restrict__ Wq,
                                                      const float* __restrict__ Wk,
                                                      const float* __restrict__ Wv,
                                                      const float* __restrict__ Wo,
                                                      u16* __restrict__ WT) {
  const int z = blockIdx.z;
  const float* W = (z == 0) ? Wq : (z == 1) ? Wk : (z == 2) ? Wv : Wo;
  u16* dst = WT + (size_t)z * DD * DD;
  __shared__ float t[32][33];
  int n0 = blockIdx.x * 32, k0 = blockIdx.y * 32;
  int tx = threadIdx.x, ty = threadIdx.y;  // 32 x 8
  #pragma unroll
  for (int r = 0; r < 32; r += 8) t[r + ty][tx] = W[(size_t)(k0 + r + ty) * DD + n0 + tx];
  __syncthreads();
  #pragma unroll
  for (int r = 0; r < 32; r += 8) dst[(size_t)(n0 + r + ty) * DD + k0 + tx] = f2bf(t[tx][r + ty]);
}

// ---- V [M][D] bf16 -> per-head V^T : Vtg[(bh*64 + d)*SS + s] ----
__global__ __launch_bounds__(256) void vtrans_kernel(const u16* __restrict__ Vb,
                                                     u16* __restrict__ Vtg) {
  __shared__ u16 T[64][72];
  int bh = blockIdx.x, st = blockIdx.y;
  int b = bh >> 4, h = bh & 15;
  const u16* src = Vb + ((size_t)(b * SS + st * 64)) * DD + h * 64;
  int r = threadIdx.x >> 3;        // 0..31
  int s8 = threadIdx.x & 7;
  #pragma unroll
  for (int half = 0; half < 2; ++half) {
    int row = half * 32 + r;
    short8 vv = *(const short8*)(src + (size_t)row * DD + s8 * 8);
    #pragma unroll
    for (int j = 0; j < 8; ++j) T[row][s8 * 8 + j] = (u16)vv[j];
  }
  __syncthreads();
  u16* dst = Vtg + ((size_t)bh * 64) * SS + st * 64;
  #pragma unroll
  for (int half = 0; half < 2; ++half) {
    int d = half * 32 + r;
    short8 ov;
    #pragma unroll
    for (int j = 0; j < 8; ++j) ov[j] = (short)T[s8 * 8 + j][d];
    *(short8*)(dst + (size_t)d * SS + s8 * 8) = ov;
  }
}

// ---- GEMM: C[M][N] = A[M][K] * Bt[N][K]^T + bias, fp32 acc ----
// AMODE 0: A bf16 in global, gload_lds staging, BK=32 (m97 path).
// AMODE 2: A fp32, reg-staged with T14 issue-early pipeline (R18-validated:
//   QKV 125->111us), BK=32. All alternatives measured worse: B dbuf (R19 +8,
//   R21 +40 via occupancy loss), BK=64 (R24 +12: occupancy 30->20%, conflicts
//   3x). B stays single-buffered; compiler schedules the 2-barrier loop best.
// QKV3: fused QKV projection — blockIdx.y in [0,24): sel = y>>3 picks the input
// tensor {q,k,v}, weight panel, bias, output buffer; sel 0 scaled by oscale.
template <int AMODE, int BF16OUT, int QKV3>
__global__ __launch_bounds__(256) void gemm_bt(const void* __restrict__ Ap0, const void* __restrict__ Ap1,
                                               const void* __restrict__ Ap2, const u16* __restrict__ Bt,
                                               const float* __restrict__ b0, const float* __restrict__ b1,
                                               const float* __restrict__ b2, void* __restrict__ Cout,
                                               float oscale, int M, int N, int K) {
  __shared__ __align__(16) u16 As[128 * 32];
  __shared__ __align__(16) u16 Bs[128 * 32];
  const int tid = threadIdx.x, lane = tid & 63, wid = tid >> 6;
  const int wr = wid >> 1, wc = wid & 1;
  const int fr = lane & 15, fq = lane >> 4;
  const int mt = blockIdx.x;
  const int ntg = blockIdx.y;
  const int sel = QKV3 ? (ntg >> 3) : 0;
  const int nt = QKV3 ? (ntg & 7) : ntg;
  const void* Ap = QKV3 ? (sel == 0 ? Ap0 : sel == 1 ? Ap1 : Ap2) : Ap0;

  f32x4 acc[4][4];
  #pragma unroll
  for (int m = 0; m < 4; ++m)
    #pragma unroll
    for (int n = 0; n < 4; ++n) acc[m][n] = (f32x4)0.0f;

  const int sRow = lane >> 2;              // bf16 staging: 16 rows/KB chunk
  const int sCol = (lane & 3) * 8;

  const float* gA32 = (const float*)Ap + (size_t)(mt * 128) * K;
  const u16*   gA16 = (const u16*)Ap + (size_t)(mt * 128) * K;
  const u16*   gB   = Bt + (QKV3 ? (size_t)sel * DD * DD : 0) + (size_t)(nt * 128) * K;

  // AMODE==2 pipeline registers (rows rA and rA+64, same column)
  const int rA = tid >> 2;
  const int cA = (tid & 3) * 8;
  f32x4 p0lo, p0hi, p1lo, p1hi;
  if (AMODE == 2) {
    const float* s0 = gA32 + (size_t)rA * K + cA;
    const float* s1 = gA32 + (size_t)(rA + 64) * K + cA;
    p0lo = *(const f32x4*)(s0);     p0hi = *(const f32x4*)(s0 + 4);
    p1lo = *(const f32x4*)(s1);     p1hi = *(const f32x4*)(s1 + 4);
  }

  for (int kt = 0; kt < K; kt += 32) {
    __syncthreads();
    if (AMODE == 2) {
      // pack + write the values loaded during the PREVIOUS iteration's MFMA phase
      u32x4 w;
      w[0] = pk_bf16(p0lo[0], p0lo[1]); w[1] = pk_bf16(p0lo[2], p0lo[3]);
      w[2] = pk_bf16(p0hi[0], p0hi[1]); w[3] = pk_bf16(p0hi[2], p0hi[3]);
      *(u32x4*)(As + rA * 32 + cA) = w;
      w[0] = pk_bf16(p1lo[0], p1lo[1]); w[1] = pk_bf16(p1lo[2], p1lo[3]);
      w[2] = pk_bf16(p1hi[0], p1hi[1]); w[3] = pk_bf16(p1hi[2], p1hi[3]);
      *(u32x4*)(As + (rA + 64) * 32 + cA) = w;
    } else {
      #pragma unroll
      for (int r = 0; r < 2; ++r) {
        int ci = r * 4 + wid;
        gload_lds16(gA16 + (size_t)(ci * 16 + sRow) * K + kt + sCol, (char*)As + ci * 1024);
      }
    }
    #pragma unroll
    for (int r = 0; r < 2; ++r) {
      int ci = r * 4 + wid;
      gload_lds16(gB + (size_t)(ci * 16 + sRow) * K + kt + sCol, (char*)Bs + ci * 1024);
    }
    __syncthreads();

    if (AMODE == 2 && kt + 32 < K) {
      // issue-early: next step's A loads fly under the MFMA phase below
      const float* s0 = gA32 + (size_t)rA * K + kt + 32 + cA;
      const float* s1 = gA32 + (size_t)(rA + 64) * K + kt + 32 + cA;
      p0lo = *(const f32x4*)(s0);     p0hi = *(const f32x4*)(s0 + 4);
      p1lo = *(const f32x4*)(s1);     p1hi = *(const f32x4*)(s1 + 4);
    }

    short8 a[4], b[4];
    #pragma unroll
    for (int m = 0; m < 4; ++m)
      a[m] = *(const short8*)(As + (wr * 64 + m * 16 + fr) * 32 + fq * 8);
    #pragma unroll
    for (int n = 0; n < 4; ++n)
      b[n] = *(const short8*)(Bs + (wc * 64 + n * 16 + fr) * 32 + fq * 8);
    #pragma unroll
    for (int m = 0; m < 4; ++m)
      #pragma unroll
      for (int n = 0; n < 4; ++n)
        acc[m][n] = __builtin_amdgcn_mfma_f32_16x16x32_bf16(a[m], b[n], acc[m][n], 0, 0, 0);
  }

  const float* bias = QKV3 ? (sel == 0 ? b0 : sel == 1 ? b1 : b2) : b0;
  const float os = (QKV3 && sel != 0) ? 1.0f : oscale;
  u16* dst16 = (u16*)Cout + (QKV3 ? (size_t)sel * MM * DD : 0);

  const int rowBase = mt * 128 + wr * 64;
  const int colBase = nt * 128 + wc * 64;
  #pragma unroll
  for (int n = 0; n < 4; ++n) {
    int col = colBase + n * 16 + fr;
    float bi = bias[col];
    #pragma unroll
    for (int m = 0; m < 4; ++m) {
      #pragma unroll
      for (int r2 = 0; r2 < 4; ++r2) {
        int row = rowBase + m * 16 + fq * 4 + r2;
        float v = (acc[m][n][r2] + bi) * os;
        if (BF16OUT) dst16[(size_t)row * N + col] = f2bf(v);
        else         ((float*)Cout)[(size_t)row * N + col] = v;
      }
    }
  }
}

// ---- flash attention, swapped-QK^T, 32x32x16 MFMA, static-max softmax ----
// R16 kernel (validated): R3 structure + per-kvb interleaved COMPUTE,
// __launch_bounds__(256,2). (256,3) is RETIRED — R10 miscompiled under that cap.
__global__ __launch_bounds__(256, 2) void attn_kernel(const u16* __restrict__ Qb,
                                                      const u16* __restrict__ Kb,
                                                      const u16* __restrict__ Vtg,
                                                      u16* __restrict__ Ob) {
  __shared__ __align__(16) u16 Ks[2][64 * 64];   // [kv][d], swizzled
  __shared__ __align__(16) u16 Vts[2][64 * 64];  // [d][kv], swizzled
  __shared__ float sbuf[4][2][32];

  const int tid = threadIdx.x, lane = tid & 63, wid = tid >> 6;
  const int l31 = lane & 31, hi = lane >> 5;
  const int bh = blockIdx.x, qt = blockIdx.y;
  const int b = bh >> 4, h = bh & 15;
  const size_t hb = (size_t)b * SS * DD + h * 64;
  const int swz = (lane & 7) << 4;                        // read-side XOR (bytes)
  const int lslot8 = ((lane & 7) ^ (lane >> 3)) * 8;      // stage source slot (elems)
  const int srow = lane >> 3;

  // Q fragments (B operand): col q = l31, k = d = c*16 + hi*8 + j
  const int qrow0 = qt * 256 + wid * 64;
  short8 qf[2][4];
  #pragma unroll
  for (int qb = 0; qb < 2; ++qb)
    #pragma unroll
    for (int c = 0; c < 4; ++c)
      qf[qb][c] = *(const short8*)(Qb + hb + (size_t)(qrow0 + qb * 32 + l31) * DD + c * 16 + hi * 8);

  f32x16 Oa[2][2];
  #pragma unroll
  for (int qb = 0; qb < 2; ++qb)
    #pragma unroll
    for (int dblk = 0; dblk < 2; ++dblk) Oa[qb][dblk] = (f32x16)0.0f;
  float lrow[2] = {0.0f, 0.0f};

  // staging base pointers (incremental, uniform k-tile stride)
  const u16* kS = Kb + hb + (size_t)(wid * 16 + srow) * DD + lslot8;
  const u16* vS = Vtg + ((size_t)bh * 64 + wid * 16 + srow) * SS + lslot8;
  char* kD = (char*)Ks[0] + wid * 2048;
  char* vD = (char*)Vts[0] + wid * 2048;

  auto STAGE = [&](int t, int b2) {
    gload_lds16(kS + (size_t)t * 64 * DD,          kD + b2 * 8192);
    gload_lds16(kS + (size_t)t * 64 * DD + 8 * DD, kD + b2 * 8192 + 1024);
    gload_lds16(vS + t * 64,                       vD + b2 * 8192);
    gload_lds16(vS + t * 64 + 8 * SS,              vD + b2 * 8192 + 1024);
  };

  auto COMPUTE = [&](int b2) {
    const char* Kt = (const char*)Ks[b2];
    const char* Vt = (const char*)Vts[b2];
    short8 PA[2][4];
    float ls[2] = {0.0f, 0.0f};

    // interleaved per-kvb: QK MFMA -> exp2 -> pack, one 32-kv half at a time
    #pragma unroll
    for (int kvb = 0; kvb < 2; ++kvb) {
      short8 kf[4];
      #pragma unroll
      for (int c = 0; c < 4; ++c)
        kf[c] = *(const short8*)(Kt + (kvb * 32 + l31) * 128 + ((c * 32 + hi * 16) ^ swz));
      #pragma unroll
      for (int qb = 0; qb < 2; ++qb) {
        f32x16 s = (f32x16)0.0f;
        __builtin_amdgcn_s_setprio(1);
        #pragma unroll
        for (int c = 0; c < 4; ++c)
          s = __builtin_amdgcn_mfma_f32_32x32x16_bf16(kf[c], qf[qb][c], s, 0, 0, 0);
        __builtin_amdgcn_s_setprio(0);
        // s[r] = S^T[kv = kvb*32 + (r&3)+8*(r>>2)+4*hi][q = qrow0 + qb*32 + l31]

        float p[16];
        #pragma unroll
        for (int r = 0; r < 16; ++r) p[r] = ex2(s[r]);

        float t8[8];
        #pragma unroll
        for (int i = 0; i < 8; ++i) t8[i] = p[2 * i] + p[2 * i + 1];
        ls[qb] += ((t8[0] + t8[1]) + (t8[2] + t8[3])) + ((t8[4] + t8[5]) + (t8[6] + t8[7]));

        // redistribute to PV A-frag layout via cvt_pk + half-swap
        unsigned w0, w1, w2, w3;
        unsigned A0 = pk_bf16(p[0], p[1]),   A1 = pk_bf16(p[2], p[3]);
        unsigned B0 = pk_bf16(p[4], p[5]),   B1 = pk_bf16(p[6], p[7]);
        swap_half(A0, B0, w0, w2); swap_half(A1, B1, w1, w3);
        u32x4 t0; t0[0] = w0; t0[1] = w1; t0[2] = w2; t0[3] = w3;
        PA[qb][kvb * 2] = __builtin_bit_cast(short8, t0);
        unsigned C0 = pk_bf16(p[8], p[9]),   C1 = pk_bf16(p[10], p[11]);
        unsigned D0 = pk_bf16(p[12], p[13]), D1 = pk_bf16(p[14], p[15]);
        swap_half(C0, D0, w0, w2); swap_half(C1, D1, w1, w3);
        u32x4 t1; t1[0] = w0; t1[1] = w1; t1[2] = w2; t1[3] = w3;
        PA[qb][kvb * 2 + 1] = __builtin_bit_cast(short8, t1);
      }
    }
    #pragma unroll
    for (int qb = 0; qb < 2; ++qb)
      lrow[qb] += ls[qb] + xchg_half(ls[qb]);

    // PV: A = P frags, B = V^T rows (row d = dblk*32 + l31, k = kv)
    __builtin_amdgcn_s_setprio(1);
    #pragma unroll
    for (int dblk = 0; dblk < 2; ++dblk)
      #pragma unroll
      for (int kvc = 0; kvc < 4; ++kvc) {
        short8 vf = *(const short8*)(Vt + (dblk * 32 + l31) * 128 + ((kvc * 32 + hi * 16) ^ swz));
        Oa[0][dblk] = __builtin_amdgcn_mfma_f32_32x32x16_bf16(PA[0][kvc], vf, Oa[0][dblk], 0, 0, 0);
        Oa[1][dblk] = __builtin_amdgcn_mfma_f32_32x32x16_bf16(PA[1][kvc], vf, Oa[1][dblk], 0, 0, 0);
      }
    __builtin_amdgcn_s_setprio(0);
  };

  STAGE(0, 0);
  __syncthreads();

  #pragma unroll 1
  for (int kt = 0; kt < SS / 64; kt += 2) {
    STAGE(kt + 1, 1);
    COMPUTE(0);
    __syncthreads();
    if (kt + 2 < SS / 64) STAGE(kt + 2, 0);
    COMPUTE(1);
    __syncthreads();
  }

  // epilogue: redistribute 1/l per q-row via per-wave LDS (same-wave, no barrier)
  #pragma unroll
  for (int qb = 0; qb < 2; ++qb)
    if (!hi) sbuf[wid][qb][l31] = 1.0f / lrow[qb];
  #pragma unroll
  for (int qb = 0; qb < 2; ++qb)
    #pragma unroll
    for (int r = 0; r < 16; ++r) {
      float inv = sbuf[wid][qb][(r & 3) + 8 * (r >> 2) + 4 * hi];
      int qrow = qrow0 + qb * 32 + (r & 3) + 8 * (r >> 2) + 4 * hi;
      size_t orow = (size_t)(b * SS + qrow) * DD + h * 64;
      Ob[orow + l31]      = f2bf(Oa[qb][0][r] * inv);
      Ob[orow + 32 + l31] = f2bf(Oa[qb][1][r] * inv);
    }
}

extern "C" void kernel_launch(void* const* d_in, const int* in_sizes, int n_in,
                              void* d_out, int out_size, void* d_ws, size_t ws_size,
                              hipStream_t stream) {
  const float* q  = (const float*)d_in[0];
  const float* k  = (const float*)d_in[1];
  const float* v  = (const float*)d_in[2];
  const float* Wq = (const float*)d_in[3];
  const float* bq = (const float*)d_in[4];
  const float* Wk = (const float*)d_in[5];
  const float* bk = (const float*)d_in[6];
  const float* Wv = (const float*)d_in[7];
  const float* bv = (const float*)d_in[8];
  const float* Wo = (const float*)d_in[9];
  const float* bo = (const float*)d_in[10];
  float* out = (float*)d_out;

  u16* WT   = (u16*)d_ws;                  // 4 x DD*DD bf16 (Wq,Wk,Wv,Wo transposed)
  u16* Qb   = WT + (size_t)4 * DD * DD;    // Qb,Kb,Vb contiguous (fused epilogue)
  u16* Kb   = Qb + (size_t)MM * DD;
  u16* Vb   = Kb + (size_t)MM * DD;
  u16* Vtg  = Vb + (size_t)MM * DD;        // per-(b,h) V^T panels [bh*64+d][SS]
  u16* AOut = Vb;                          // V rows dead after vtrans

  wtrans4_kernel<<<dim3(32, 32, 4), dim3(32, 8), 0, stream>>>(Wq, Wk, Wv, Wo, WT);

  // Fused QKV projection, reg-staged fp32 A with issue-early pipeline (AMODE=2).
  gemm_bt<2, 1, 1><<<dim3(MM / 128, 24), 256, 0, stream>>>(
      q, k, v, WT, bq, bk, bv, Qb, SLOG2E, MM, DD, DD);

  vtrans_kernel<<<dim3(64, 32), 256, 0, stream>>>(Vb, Vtg);
  attn_kernel<<<dim3(64, 8), 256, 0, stream>>>(Qb, Kb, Vtg, AOut);
  gemm_bt<0, 0, 0><<<dim3(MM / 128, DD / 128), 256, 0, stream>>>(
      AOut, nullptr, nullptr, WT + (size_t)3 * DD * DD, bo, nullptr, nullptr, out, 1.0f, MM, DD, DD);
}